// Round 12
// baseline (12441.881 us; speedup 1.0000x reference)
//
#include <hip/hip_runtime.h>

#define HDIM 2048
#define TSTEPS 1024
#define NBLK 128
#define NTHR 512
#define CPB 16
#define TAGM 0x3FFu
#define NREP 8
#define RSTRIDE 2112u   // u32 per replica = 8KB + 256B (channel decorrelation)
#define SPIN_CAP (1 << 21)   // watchdog: ~1s, never reached in normal runs

typedef unsigned long long ull;

__device__ __forceinline__ int snake_src(int t) {
    int y = t >> 5, p = t & 31;
    return (y & 1) ? (y * 32 + 31 - p) : t;
}
__device__ __forceinline__ float sigmoid_f(float v) {
    return __builtin_amdgcn_rcpf(1.f + __expf(-v));
}
__device__ __forceinline__ float tanh_f(float v) {
    return 1.f - 2.f * __builtin_amdgcn_rcpf(__expf(2.f * v) + 1.f);
}
// broadcast from lane ((lane & 0x30) | J) : and=0x10 keeps bit 4, or=J
// (bits 0..3); bit 5 (32-lane half) is implicitly preserved. 16-lane
// groups (lane>>4 within the wave) are closed under this swizzle.
template<int J>
__device__ __forceinline__ float bcast16(float v) {
    return __uint_as_float((unsigned)__builtin_amdgcn_ds_swizzle(
        (int)__float_as_uint(v), (J << 5) | 0x10));
}

// raw barrier: drain LDS only; vmem (tag prefetch) stays in flight.
#define BAR_RAW() do { asm volatile("s_waitcnt lgkmcnt(0)" ::: "memory"); \
                       __builtin_amdgcn_s_barrier(); } while (0)

// ---------------------------------------------------------------------------
// R12 = the R10 theory (halve publishers + halve poll traffic) on a
// SPILL-PROOF shape: 128 blocks x 512 threads (16 cols/block).
//   Ledger L5 (R10/R11): 1024-thread blocks make hipcc cap VGPR at 64 ->
//   96-reg weight array spills to scratch -> +37% dur. 512-thread blocks
//   allocated correctly in every passing round. VGPR_Count is the check.
//   - thread = (r = tid>>4, c = tid&15): 64 rows x 1 col, 192 weight regs,
//     192 FMAs (double R9 — accepted ~+200cyc, partially hidden).
//   - poll: R9-exact 16B/thread (2 ulls, rows 4tid..4tid+3); 16-lane group
//     g covers rows 64g..64g+63; bcast16<J> delivers member J's 4 rows.
//   - publishers: 128 (was 256) -> smaller max-over-publishers tail.
//     pollers: 65536 (was 131072) -> half the L3 poll queueing (R3's
//     mechanism, third helping). pollers/replica = 16 blk x 512.
//   - publish: 8 replicas x 16 cols = 128 dwords = 2 dword stores per
//     finalizer lane. 64KB/step, 2048 sectors — R3-identical (L1/L4).
//   - election old==7 (8 waves); reduce = shfl m=16,32 + ds_add.
// Carried: self-bypass sNext (4 threads: tid>>2==blk), tag prefetch +
// immediate reload, single raw barrier (L2), sleep backoff (L3), watchdog.
// ---------------------------------------------------------------------------
__global__ __launch_bounds__(NTHR, 1) void gru_all(
    const float* __restrict__ x,
    const float* __restrict__ We,  const float* __restrict__ be,
    const float* __restrict__ Wir, const float* __restrict__ bir,
    const float* __restrict__ Wiz, const float* __restrict__ biz,
    const float* __restrict__ Win, const float* __restrict__ bin_,
    const float* __restrict__ Whr, const float* __restrict__ Whz,
    const float* __restrict__ Whn, const float* __restrict__ bhn,
    float* __restrict__ out, unsigned* __restrict__ u0, unsigned* __restrict__ u1)
{
    const int tid  = threadIdx.x;
    const int blk  = blockIdx.x;
    const int c    = tid & 15;
    const int r    = tid >> 4;            // 0..31
    const int col  = blk * CPB + c;
    const int row0 = r * 64;
    const int lane = tid & 63, wv = tid >> 6;   // 8 waves

    __shared__ float red[8][6][16];       // init-phase cross-wave reduce
    __shared__ float sX[TSTEPS];          // x in snake order
    __shared__ float sAcc[3][16];         // per-step gate accumulators
    __shared__ float sNext[16];           // own 16 cols of h_t (full precision)
    __shared__ float sAN[16];             // input-path n-term for current t
    __shared__ float sVr[16], sVz[16], sVn[16];   // rank-1 row-sums (const)
    __shared__ float sCr[16], sCz[16], sCn[16];   // bias-path consts
    __shared__ float sBh[16];                     // bhn consts
    __shared__ unsigned sCnt;             // waves-done counter

    // ---- one-time: x (snake order) into LDS ----
    for (int i = tid; i < TSTEPS; i += NTHR) sX[i] = x[snake_src(i)];
    if (tid == 0) sCnt = 0u;

    // ---- recurrent weights into registers (one-time): 64 rows x 3 ----
    float wr[64], wz[64], wn[64];
#pragma unroll 8
    for (int k = 0; k < 64; ++k) {
        size_t off = (size_t)(row0 + k) * HDIM + col;
        wr[k] = Whr[off];
        wz[k] = Whz[off];
        wn[k] = Whn[off];
    }

    // ---- rank-1 input-path constants (We/be direct from global) ----
    float eR=0,eZ=0,eN=0,bRa=0,bZa=0,bNa=0;
#pragma unroll 8
    for (int k = 0; k < 64; ++k) {
        int row = row0 + k;
        size_t off = (size_t)row * HDIM + col;
        float we = We[row], bb = be[row];
        float w0 = Wir[off], w1 = Wiz[off], w2 = Win[off];
        eR  = fmaf(we, w0, eR);  bRa = fmaf(bb, w0, bRa);
        eZ  = fmaf(we, w1, eZ);  bZa = fmaf(bb, w1, bZa);
        eN  = fmaf(we, w2, eN);  bNa = fmaf(bb, w2, bNa);
    }
    // in-wave reduce over the wave's 4 r-groups (bits 4,5 of lane)
#pragma unroll
    for (int m = 16; m < 64; m <<= 1) {
        eR  += __shfl_xor(eR,  m, 64); eZ  += __shfl_xor(eZ,  m, 64);
        eN  += __shfl_xor(eN,  m, 64); bRa += __shfl_xor(bRa, m, 64);
        bZa += __shfl_xor(bZa, m, 64); bNa += __shfl_xor(bNa, m, 64);
    }
    if (lane < 16) {
        red[wv][0][lane]=eR;  red[wv][1][lane]=eZ;  red[wv][2][lane]=eN;
        red[wv][3][lane]=bRa; red[wv][4][lane]=bZa; red[wv][5][lane]=bNa;
    }
    __syncthreads();   // red + sX staged

    unsigned pk1 = 0;
    if (tid < 16) {
        float vrc=0,vzc=0,vnc=0,crc=0,czc=0,cnc=0;
#pragma unroll
        for (int w = 0; w < 8; ++w) {
            vrc += red[w][0][tid]; vzc += red[w][1][tid]; vnc += red[w][2][tid];
            crc += red[w][3][tid]; czc += red[w][4][tid]; cnc += red[w][5][tid];
        }
        crc += bir[col]; czc += biz[col]; cnc += bin_[col];
        float bhc = bhn[col];

        // constants -> LDS so ANY wave can finalize/re-init
        sVr[tid]=vrc; sVz[tid]=vzc; sVn[tid]=vnc;
        sCr[tid]=crc; sCz[tid]=czc; sCn[tid]=cnc; sBh[tid]=bhc;

        // ---- step 0: h_0 == 0, fully local; h_1 with tag 1 ----
        float x0 = sX[0];
        float ar = fmaf(x0, vrc, crc);
        float az = fmaf(x0, vzc, czc);
        float an = fmaf(x0, vnc, cnc);
        float rg = sigmoid_f(ar), zg = sigmoid_f(az);
        float ng = tanh_f(fmaf(rg, bhc, an));
        float h1 = (1.f - zg) * ng;
        pk1 = ((__float_as_uint(h1) + 512u) & ~TAGM) | 1u;
        sNext[tid] = h1;                  // self-bypass seed for t=1

        // seed t=1 accumulators + n-term
        float x1 = sX[1];
        sAcc[0][tid] = fmaf(x1, vrc, crc);
        sAcc[1][tid] = fmaf(x1, vzc, czc);
        sAN[tid]     = fmaf(x1, vnc, cnc);
        sAcc[2][tid] = bhc;
    }
    // step-0 publish: 8 replicas via TWO dword stores per wave0 lane
    if (wv == 0) {
        unsigned pkb = __shfl(pk1, lane & 15, 64);
        unsigned idx = (unsigned)blk * 16u + (unsigned)(lane & 15);
        __hip_atomic_store(&u1[(unsigned)(lane >> 4) * RSTRIDE + idx],
                           pkb, __ATOMIC_RELAXED, __HIP_MEMORY_SCOPE_AGENT);
        __hip_atomic_store(&u1[((unsigned)(lane >> 4) + 4u) * RSTRIDE + idx],
                           pkb, __ATOMIC_RELAXED, __HIP_MEMORY_SCOPE_AGENT);
    }
    __syncthreads();   // LDS state + publish issued before anyone polls

    const ull  M2     = 0x000003FF000003FFull;
    const ull  repoff = (ull)(blk & 7) * (RSTRIDE / 2);   // ull units
    const bool selfcol = ((tid >> 2) == blk);   // polls 4 of own 16 cols
    int alive = 1;     // watchdog flag: once 0, never poll again

    // ---- initial prefetch for t=1: two ulls (rows 4tid..4tid+3) ----
    ull v0p, v1p;
    {
        const ull* pp1 = (const ull*)u1 + repoff + 2 * tid;
        v0p = __hip_atomic_load(&pp1[0], __ATOMIC_RELAXED, __HIP_MEMORY_SCOPE_AGENT);
        v1p = __hip_atomic_load(&pp1[1], __ATOMIC_RELAXED, __HIP_MEMORY_SCOPE_AGENT);
    }

    for (int t = 1; t < TSTEPS; ++t) {
        const unsigned* pin  = (t & 1) ? u1 : u0;
        unsigned*       pout = (t & 1) ? u0 : u1;
        const unsigned  tg   = (unsigned)t & TAGM;
        const ull       tg2  = ((ull)tg << 32) | (ull)tg;

        float hr0, hr1, hr2, hr3;
        if (selfcol) {
            // own columns: values live in LDS, skip the L3 round-trip
            const float* sn = &sNext[(tid & 3) * 4];
            hr0 = sn[0]; hr1 = sn[1]; hr2 = sn[2]; hr3 = sn[3];
        } else {
            ull v0 = v0p, v1 = v1p;
            if (((v0 ^ tg2) | (v1 ^ tg2)) & M2) {
                const ull* pp = (const ull*)pin + repoff + 2 * tid;
                // immediate reload (no sleep): prefetch is usually stale-by-
                // timing; a publish may have landed during our FMA phase.
                v0 = __hip_atomic_load(&pp[0], __ATOMIC_RELAXED, __HIP_MEMORY_SCOPE_AGENT);
                v1 = __hip_atomic_load(&pp[1], __ATOMIC_RELAXED, __HIP_MEMORY_SCOPE_AGENT);
                if ((((v0 ^ tg2) | (v1 ^ tg2)) & M2) && alive) {
                    int guard = 0;
                    do {
                        __builtin_amdgcn_s_sleep(1);
                        v0 = __hip_atomic_load(&pp[0], __ATOMIC_RELAXED, __HIP_MEMORY_SCOPE_AGENT);
                        v1 = __hip_atomic_load(&pp[1], __ATOMIC_RELAXED, __HIP_MEMORY_SCOPE_AGENT);
                        if (++guard > SPIN_CAP) { alive = 0; break; }
                    } while (((v0 ^ tg2) | (v1 ^ tg2)) & M2);
                }
            }
            hr0 = __uint_as_float((unsigned)v0         & ~TAGM);
            hr1 = __uint_as_float((unsigned)(v0 >> 32) & ~TAGM);
            hr2 = __uint_as_float((unsigned)v1         & ~TAGM);
            hr3 = __uint_as_float((unsigned)(v1 >> 32) & ~TAGM);
        }

        // ---- 64 swizzle broadcasts + 192 FMAs (no barrier) ----
        float a0 = 0.f, a1 = 0.f, a2 = 0.f;
#define GRP(J) { \
        float h0 = bcast16<J>(hr0), h1 = bcast16<J>(hr1); \
        float h2 = bcast16<J>(hr2), h3 = bcast16<J>(hr3); \
        a0 = fmaf(h0, wr[4*J+0], a0); a1 = fmaf(h0, wz[4*J+0], a1); a2 = fmaf(h0, wn[4*J+0], a2); \
        a0 = fmaf(h1, wr[4*J+1], a0); a1 = fmaf(h1, wz[4*J+1], a1); a2 = fmaf(h1, wn[4*J+1], a2); \
        a0 = fmaf(h2, wr[4*J+2], a0); a1 = fmaf(h2, wz[4*J+2], a1); a2 = fmaf(h2, wn[4*J+2], a2); \
        a0 = fmaf(h3, wr[4*J+3], a0); a1 = fmaf(h3, wz[4*J+3], a1); a2 = fmaf(h3, wn[4*J+3], a2); }
        GRP(0)  GRP(1)  GRP(2)  GRP(3)  GRP(4)  GRP(5)  GRP(6)  GRP(7)
        GRP(8)  GRP(9)  GRP(10) GRP(11) GRP(12) GRP(13) GRP(14) GRP(15)
#undef GRP

        // ---- reduce over the wave's 4 r-groups (2 stages) ----
#pragma unroll
        for (int m = 16; m < 64; m <<= 1) {
            a0 += __shfl_xor(a0, m, 64);
            a1 += __shfl_xor(a1, m, 64);
            a2 += __shfl_xor(a2, m, 64);
        }
        if (lane < 16) {
            atomicAdd(&sAcc[0][lane], a0);
            atomicAdd(&sAcc[1][lane], a1);
            atomicAdd(&sAcc[2][lane], a2);
        }

        // ---- prefetch t+1 slots; stays in flight across the barrier ----
        {
            const ull* ppn = (const ull*)pout + repoff + 2 * tid;
            v0p = __hip_atomic_load(&ppn[0], __ATOMIC_RELAXED, __HIP_MEMORY_SCOPE_AGENT);
            v1p = __hip_atomic_load(&ppn[1], __ATOMIC_RELAXED, __HIP_MEMORY_SCOPE_AGENT);
        }

        // ---- last-finisher election: wave seeing old==7 finalizes NOW ----
        unsigned oldv = 0;
        if (lane == 0) oldv = atomicAdd(&sCnt, 1u);
        oldv = __builtin_amdgcn_readfirstlane(oldv);
        if (oldv == 7u) {
            float hnew = 0.f; unsigned pk = 0;
            if (lane < 16) {
                float Sr = sAcc[0][lane];         // aR + Whr.h
                float Sz = sAcc[1][lane];         // aZ + Whz.h
                float Sn = sAcc[2][lane];         // bhn + Whn.h
                float hold = sNext[lane];         // own h_t, full precision
                float rg = sigmoid_f(Sr), zg = sigmoid_f(Sz);
                float ng = tanh_f(sAN[lane] + rg * Sn);
                hnew = (1.f - zg) * ng + zg * hold;
                pk = ((__float_as_uint(hnew) + 512u) & ~TAGM)
                   | ((unsigned)(t + 1) & TAGM);
            }
            if (t == TSTEPS - 1) {
                if (lane < 16) out[blk * CPB + lane] = hnew;
            } else {
                unsigned pkb = __shfl(pk, lane & 15, 64);
                unsigned idx = (unsigned)blk * 16u + (unsigned)(lane & 15);
                __hip_atomic_store(&pout[(unsigned)(lane >> 4) * RSTRIDE + idx],
                                   pkb, __ATOMIC_RELAXED, __HIP_MEMORY_SCOPE_AGENT);
                __hip_atomic_store(&pout[((unsigned)(lane >> 4) + 4u) * RSTRIDE + idx],
                                   pkb, __ATOMIC_RELAXED, __HIP_MEMORY_SCOPE_AGENT);
                if (lane < 16) {   // self-bypass + re-init for t+1
                    sNext[lane] = hnew;
                    float xn = sX[t + 1];
                    sAcc[0][lane] = fmaf(xn, sVr[lane], sCr[lane]);
                    sAcc[1][lane] = fmaf(xn, sVz[lane], sCz[lane]);
                    sAN[lane]     = fmaf(xn, sVn[lane], sCn[lane]);
                    sAcc[2][lane] = sBh[lane];
                }
                if (lane == 0) sCnt = 0u;
            }
        }
        // single barrier: publish issued + LDS re-init done before anyone
        // proceeds to t+1 (ledger L2); vmem prefetch stays in flight.
        BAR_RAW();
    }
}

extern "C" void kernel_launch(void* const* d_in, const int* in_sizes, int n_in,
                              void* d_out, int out_size, void* d_ws, size_t ws_size,
                              hipStream_t stream) {
    const float* x    = (const float*)d_in[0];
    const float* We   = (const float*)d_in[1];
    const float* be   = (const float*)d_in[2];
    const float* Wir  = (const float*)d_in[3];
    const float* bir  = (const float*)d_in[4];
    const float* Wiz  = (const float*)d_in[5];
    const float* biz  = (const float*)d_in[6];
    const float* Win  = (const float*)d_in[7];
    const float* bin_ = (const float*)d_in[8];
    const float* Whr  = (const float*)d_in[9];
    const float* Whz  = (const float*)d_in[10];
    const float* Whn  = (const float*)d_in[11];
    const float* bhn  = (const float*)d_in[12];

    unsigned* u0 = (unsigned*)d_ws;             // even parity: 8 replicas
    unsigned* u1 = u0 + NREP * RSTRIDE;         // odd parity:  8 replicas
    // total workspace use: 2 * 8 * 2112 * 4B = 132 KB

    gru_all<<<NBLK, NTHR, 0, stream>>>(x, We, be, Wir, bir, Wiz, biz, Win, bin_,
                                       Whr, Whz, Whn, bhn,
                                       (float*)d_out, u0, u1);
}

// Round 13
// 2696.338 us; speedup vs baseline: 4.6144x; 4.6144x over previous
//
#include <hip/hip_runtime.h>

#define HDIM 2048
#define TSTEPS 1024
#define NBLK 128
#define NTHR 512
#define CPB 16
#define TAGM 0x3FFu
#define NREP 8
#define RSTRIDE 2112u   // u32 per replica = 8KB + 256B (channel decorrelation)
#define SPIN_CAP (1 << 21)   // watchdog: ~1s, never reached in normal runs

typedef unsigned long long ull;

__device__ __forceinline__ int snake_src(int t) {
    int y = t >> 5, p = t & 31;
    return (y & 1) ? (y * 32 + 31 - p) : t;
}
__device__ __forceinline__ float sigmoid_f(float v) {
    return __builtin_amdgcn_rcpf(1.f + __expf(-v));
}
__device__ __forceinline__ float tanh_f(float v) {
    return 1.f - 2.f * __builtin_amdgcn_rcpf(__expf(2.f * v) + 1.f);
}
// broadcast from lane ((lane & 0x30) | J) : and=0x10 keeps bit 4, or=J
// (bits 0..3); bit 5 (32-lane half) is implicitly preserved. 16-lane
// groups (lane>>4 within the wave) are closed under this swizzle.
template<int J>
__device__ __forceinline__ float bcast16(float v) {
    return __uint_as_float((unsigned)__builtin_amdgcn_ds_swizzle(
        (int)__float_as_uint(v), (J << 5) | 0x10));
}

// raw barrier: drain LDS only; vmem (tag prefetch) stays in flight.
#define BAR_RAW() do { asm volatile("s_waitcnt lgkmcnt(0)" ::: "memory"); \
                       __builtin_amdgcn_s_barrier(); } while (0)

// ---------------------------------------------------------------------------
// R13 = R12 with the scratch-array bug fixed (rule #20): R12's weight-load
// loop was `#pragma unroll 8` over k<64 — PARTIAL unroll -> wr[k] runtime-
// indexed -> all 192 weights allocated in SCRATCH (VGPR_Count=28, FETCH
// 25GB, 12.4ms). The loop below is FULLY unrolled: every access compile-
// time-indexed, arrays promote to registers (~230 VGPR, fits 256 budget).
// The R12 theory (halve publishers + halve poll traffic) is still untested
// until this runs clean; VGPR_Count >= 200 is the go/no-go check.
//
// Shape: 128 blocks x 512 threads, 16 cols/block.
//   - thread = (r = tid>>4, c = tid&15): 64 rows x 1 col, 192 weight regs,
//     192 FMAs (double R9 — accepted ~+200cyc, partially hidden).
//   - poll: R9-exact 16B/thread (2 ulls = rows 4tid..4tid+3); 16-lane
//     group g covers rows 64g..64g+63; bcast16<J> delivers member J's rows.
//   - publishers: 128 (was 256) -> smaller max-over-publishers tail.
//     pollers: 65536 (was 131072) -> half the L3 poll queueing (R3's
//     mechanism). pollers/replica = 16 blk x 512 (unchanged).
//   - publish: 8 replicas x 16 cols = 2 dword stores per finalizer lane;
//     64KB/step, 2048 sectors — R3-identical (ledger L1/L4).
//   - election old==7 (8 waves); reduce = shfl m=16,32 + ds_add.
// Carried: self-bypass sNext (tid>>2==blk), tag prefetch + immediate
// reload, single raw barrier (L2), sleep backoff (L3), watchdog (R7).
// Ledger L5 (revised): NEVER partially-unroll a loop that writes a
// register-resident array — runtime indexing forces scratch.
// ---------------------------------------------------------------------------
__global__ __launch_bounds__(NTHR, 1) void gru_all(
    const float* __restrict__ x,
    const float* __restrict__ We,  const float* __restrict__ be,
    const float* __restrict__ Wir, const float* __restrict__ bir,
    const float* __restrict__ Wiz, const float* __restrict__ biz,
    const float* __restrict__ Win, const float* __restrict__ bin_,
    const float* __restrict__ Whr, const float* __restrict__ Whz,
    const float* __restrict__ Whn, const float* __restrict__ bhn,
    float* __restrict__ out, unsigned* __restrict__ u0, unsigned* __restrict__ u1)
{
    const int tid  = threadIdx.x;
    const int blk  = blockIdx.x;
    const int c    = tid & 15;
    const int r    = tid >> 4;            // 0..31
    const int col  = blk * CPB + c;
    const int row0 = r * 64;
    const int lane = tid & 63, wv = tid >> 6;   // 8 waves

    __shared__ float red[8][6][16];       // init-phase cross-wave reduce
    __shared__ float sX[TSTEPS];          // x in snake order
    __shared__ float sAcc[3][16];         // per-step gate accumulators
    __shared__ float sNext[16];           // own 16 cols of h_t (full precision)
    __shared__ float sAN[16];             // input-path n-term for current t
    __shared__ float sVr[16], sVz[16], sVn[16];   // rank-1 row-sums (const)
    __shared__ float sCr[16], sCz[16], sCn[16];   // bias-path consts
    __shared__ float sBh[16];                     // bhn consts
    __shared__ unsigned sCnt;             // waves-done counter

    // ---- one-time: x (snake order) into LDS ----
    for (int i = tid; i < TSTEPS; i += NTHR) sX[i] = x[snake_src(i)];
    if (tid == 0) sCnt = 0u;

    // ---- recurrent weights into registers (one-time): 64 rows x 3 ----
    // FULL unroll: every wr/wz/wn access must be compile-time-indexed
    // (rule #20 — partial unroll sent these to scratch in R12).
    float wr[64], wz[64], wn[64];
#pragma unroll
    for (int k = 0; k < 64; ++k) {
        size_t off = (size_t)(row0 + k) * HDIM + col;
        wr[k] = Whr[off];
        wz[k] = Whz[off];
        wn[k] = Whn[off];
    }

    // ---- rank-1 input-path constants (We/be direct from global) ----
    float eR=0,eZ=0,eN=0,bRa=0,bZa=0,bNa=0;
#pragma unroll
    for (int k = 0; k < 64; ++k) {
        int row = row0 + k;
        size_t off = (size_t)row * HDIM + col;
        float we = We[row], bb = be[row];
        float w0 = Wir[off], w1 = Wiz[off], w2 = Win[off];
        eR  = fmaf(we, w0, eR);  bRa = fmaf(bb, w0, bRa);
        eZ  = fmaf(we, w1, eZ);  bZa = fmaf(bb, w1, bZa);
        eN  = fmaf(we, w2, eN);  bNa = fmaf(bb, w2, bNa);
    }
    // in-wave reduce over the wave's 4 r-groups (bits 4,5 of lane)
#pragma unroll
    for (int m = 16; m < 64; m <<= 1) {
        eR  += __shfl_xor(eR,  m, 64); eZ  += __shfl_xor(eZ,  m, 64);
        eN  += __shfl_xor(eN,  m, 64); bRa += __shfl_xor(bRa, m, 64);
        bZa += __shfl_xor(bZa, m, 64); bNa += __shfl_xor(bNa, m, 64);
    }
    if (lane < 16) {
        red[wv][0][lane]=eR;  red[wv][1][lane]=eZ;  red[wv][2][lane]=eN;
        red[wv][3][lane]=bRa; red[wv][4][lane]=bZa; red[wv][5][lane]=bNa;
    }
    __syncthreads();   // red + sX staged

    unsigned pk1 = 0;
    if (tid < 16) {
        float vrc=0,vzc=0,vnc=0,crc=0,czc=0,cnc=0;
#pragma unroll
        for (int w = 0; w < 8; ++w) {
            vrc += red[w][0][tid]; vzc += red[w][1][tid]; vnc += red[w][2][tid];
            crc += red[w][3][tid]; czc += red[w][4][tid]; cnc += red[w][5][tid];
        }
        crc += bir[col]; czc += biz[col]; cnc += bin_[col];
        float bhc = bhn[col];

        // constants -> LDS so ANY wave can finalize/re-init
        sVr[tid]=vrc; sVz[tid]=vzc; sVn[tid]=vnc;
        sCr[tid]=crc; sCz[tid]=czc; sCn[tid]=cnc; sBh[tid]=bhc;

        // ---- step 0: h_0 == 0, fully local; h_1 with tag 1 ----
        float x0 = sX[0];
        float ar = fmaf(x0, vrc, crc);
        float az = fmaf(x0, vzc, czc);
        float an = fmaf(x0, vnc, cnc);
        float rg = sigmoid_f(ar), zg = sigmoid_f(az);
        float ng = tanh_f(fmaf(rg, bhc, an));
        float h1 = (1.f - zg) * ng;
        pk1 = ((__float_as_uint(h1) + 512u) & ~TAGM) | 1u;
        sNext[tid] = h1;                  // self-bypass seed for t=1

        // seed t=1 accumulators + n-term
        float x1 = sX[1];
        sAcc[0][tid] = fmaf(x1, vrc, crc);
        sAcc[1][tid] = fmaf(x1, vzc, czc);
        sAN[tid]     = fmaf(x1, vnc, cnc);
        sAcc[2][tid] = bhc;
    }
    // step-0 publish: 8 replicas via TWO dword stores per wave0 lane
    if (wv == 0) {
        unsigned pkb = __shfl(pk1, lane & 15, 64);
        unsigned idx = (unsigned)blk * 16u + (unsigned)(lane & 15);
        __hip_atomic_store(&u1[(unsigned)(lane >> 4) * RSTRIDE + idx],
                           pkb, __ATOMIC_RELAXED, __HIP_MEMORY_SCOPE_AGENT);
        __hip_atomic_store(&u1[((unsigned)(lane >> 4) + 4u) * RSTRIDE + idx],
                           pkb, __ATOMIC_RELAXED, __HIP_MEMORY_SCOPE_AGENT);
    }
    __syncthreads();   // LDS state + publish issued before anyone polls

    const ull  M2     = 0x000003FF000003FFull;
    const ull  repoff = (ull)(blk & 7) * (RSTRIDE / 2);   // ull units
    const bool selfcol = ((tid >> 2) == blk);   // polls 4 of own 16 cols
    int alive = 1;     // watchdog flag: once 0, never poll again

    // ---- initial prefetch for t=1: two ulls (rows 4tid..4tid+3) ----
    ull v0p, v1p;
    {
        const ull* pp1 = (const ull*)u1 + repoff + 2 * tid;
        v0p = __hip_atomic_load(&pp1[0], __ATOMIC_RELAXED, __HIP_MEMORY_SCOPE_AGENT);
        v1p = __hip_atomic_load(&pp1[1], __ATOMIC_RELAXED, __HIP_MEMORY_SCOPE_AGENT);
    }

    for (int t = 1; t < TSTEPS; ++t) {
        const unsigned* pin  = (t & 1) ? u1 : u0;
        unsigned*       pout = (t & 1) ? u0 : u1;
        const unsigned  tg   = (unsigned)t & TAGM;
        const ull       tg2  = ((ull)tg << 32) | (ull)tg;

        float hr0, hr1, hr2, hr3;
        if (selfcol) {
            // own columns: values live in LDS, skip the L3 round-trip
            const float* sn = &sNext[(tid & 3) * 4];
            hr0 = sn[0]; hr1 = sn[1]; hr2 = sn[2]; hr3 = sn[3];
        } else {
            ull v0 = v0p, v1 = v1p;
            if (((v0 ^ tg2) | (v1 ^ tg2)) & M2) {
                const ull* pp = (const ull*)pin + repoff + 2 * tid;
                // immediate reload (no sleep): prefetch is usually stale-by-
                // timing; a publish may have landed during our FMA phase.
                v0 = __hip_atomic_load(&pp[0], __ATOMIC_RELAXED, __HIP_MEMORY_SCOPE_AGENT);
                v1 = __hip_atomic_load(&pp[1], __ATOMIC_RELAXED, __HIP_MEMORY_SCOPE_AGENT);
                if ((((v0 ^ tg2) | (v1 ^ tg2)) & M2) && alive) {
                    int guard = 0;
                    do {
                        __builtin_amdgcn_s_sleep(1);
                        v0 = __hip_atomic_load(&pp[0], __ATOMIC_RELAXED, __HIP_MEMORY_SCOPE_AGENT);
                        v1 = __hip_atomic_load(&pp[1], __ATOMIC_RELAXED, __HIP_MEMORY_SCOPE_AGENT);
                        if (++guard > SPIN_CAP) { alive = 0; break; }
                    } while (((v0 ^ tg2) | (v1 ^ tg2)) & M2);
                }
            }
            hr0 = __uint_as_float((unsigned)v0         & ~TAGM);
            hr1 = __uint_as_float((unsigned)(v0 >> 32) & ~TAGM);
            hr2 = __uint_as_float((unsigned)v1         & ~TAGM);
            hr3 = __uint_as_float((unsigned)(v1 >> 32) & ~TAGM);
        }

        // ---- 64 swizzle broadcasts + 192 FMAs (no barrier) ----
        float a0 = 0.f, a1 = 0.f, a2 = 0.f;
#define GRP(J) { \
        float h0 = bcast16<J>(hr0), h1 = bcast16<J>(hr1); \
        float h2 = bcast16<J>(hr2), h3 = bcast16<J>(hr3); \
        a0 = fmaf(h0, wr[4*J+0], a0); a1 = fmaf(h0, wz[4*J+0], a1); a2 = fmaf(h0, wn[4*J+0], a2); \
        a0 = fmaf(h1, wr[4*J+1], a0); a1 = fmaf(h1, wz[4*J+1], a1); a2 = fmaf(h1, wn[4*J+1], a2); \
        a0 = fmaf(h2, wr[4*J+2], a0); a1 = fmaf(h2, wz[4*J+2], a1); a2 = fmaf(h2, wn[4*J+2], a2); \
        a0 = fmaf(h3, wr[4*J+3], a0); a1 = fmaf(h3, wz[4*J+3], a1); a2 = fmaf(h3, wn[4*J+3], a2); }
        GRP(0)  GRP(1)  GRP(2)  GRP(3)  GRP(4)  GRP(5)  GRP(6)  GRP(7)
        GRP(8)  GRP(9)  GRP(10) GRP(11) GRP(12) GRP(13) GRP(14) GRP(15)
#undef GRP

        // ---- reduce over the wave's 4 r-groups (2 stages) ----
#pragma unroll
        for (int m = 16; m < 64; m <<= 1) {
            a0 += __shfl_xor(a0, m, 64);
            a1 += __shfl_xor(a1, m, 64);
            a2 += __shfl_xor(a2, m, 64);
        }
        if (lane < 16) {
            atomicAdd(&sAcc[0][lane], a0);
            atomicAdd(&sAcc[1][lane], a1);
            atomicAdd(&sAcc[2][lane], a2);
        }

        // ---- prefetch t+1 slots; stays in flight across the barrier ----
        {
            const ull* ppn = (const ull*)pout + repoff + 2 * tid;
            v0p = __hip_atomic_load(&ppn[0], __ATOMIC_RELAXED, __HIP_MEMORY_SCOPE_AGENT);
            v1p = __hip_atomic_load(&ppn[1], __ATOMIC_RELAXED, __HIP_MEMORY_SCOPE_AGENT);
        }

        // ---- last-finisher election: wave seeing old==7 finalizes NOW ----
        unsigned oldv = 0;
        if (lane == 0) oldv = atomicAdd(&sCnt, 1u);
        oldv = __builtin_amdgcn_readfirstlane(oldv);
        if (oldv == 7u) {
            float hnew = 0.f; unsigned pk = 0;
            if (lane < 16) {
                float Sr = sAcc[0][lane];         // aR + Whr.h
                float Sz = sAcc[1][lane];         // aZ + Whz.h
                float Sn = sAcc[2][lane];         // bhn + Whn.h
                float hold = sNext[lane];         // own h_t, full precision
                float rg = sigmoid_f(Sr), zg = sigmoid_f(Sz);
                float ng = tanh_f(sAN[lane] + rg * Sn);
                hnew = (1.f - zg) * ng + zg * hold;
                pk = ((__float_as_uint(hnew) + 512u) & ~TAGM)
                   | ((unsigned)(t + 1) & TAGM);
            }
            if (t == TSTEPS - 1) {
                if (lane < 16) out[blk * CPB + lane] = hnew;
            } else {
                unsigned pkb = __shfl(pk, lane & 15, 64);
                unsigned idx = (unsigned)blk * 16u + (unsigned)(lane & 15);
                __hip_atomic_store(&pout[(unsigned)(lane >> 4) * RSTRIDE + idx],
                                   pkb, __ATOMIC_RELAXED, __HIP_MEMORY_SCOPE_AGENT);
                __hip_atomic_store(&pout[((unsigned)(lane >> 4) + 4u) * RSTRIDE + idx],
                                   pkb, __ATOMIC_RELAXED, __HIP_MEMORY_SCOPE_AGENT);
                if (lane < 16) {   // self-bypass + re-init for t+1
                    sNext[lane] = hnew;
                    float xn = sX[t + 1];
                    sAcc[0][lane] = fmaf(xn, sVr[lane], sCr[lane]);
                    sAcc[1][lane] = fmaf(xn, sVz[lane], sCz[lane]);
                    sAN[lane]     = fmaf(xn, sVn[lane], sCn[lane]);
                    sAcc[2][lane] = sBh[lane];
                }
                if (lane == 0) sCnt = 0u;
            }
        }
        // single barrier: publish issued + LDS re-init done before anyone
        // proceeds to t+1 (ledger L2); vmem prefetch stays in flight.
        BAR_RAW();
    }
}

extern "C" void kernel_launch(void* const* d_in, const int* in_sizes, int n_in,
                              void* d_out, int out_size, void* d_ws, size_t ws_size,
                              hipStream_t stream) {
    const float* x    = (const float*)d_in[0];
    const float* We   = (const float*)d_in[1];
    const float* be   = (const float*)d_in[2];
    const float* Wir  = (const float*)d_in[3];
    const float* bir  = (const float*)d_in[4];
    const float* Wiz  = (const float*)d_in[5];
    const float* biz  = (const float*)d_in[6];
    const float* Win  = (const float*)d_in[7];
    const float* bin_ = (const float*)d_in[8];
    const float* Whr  = (const float*)d_in[9];
    const float* Whz  = (const float*)d_in[10];
    const float* Whn  = (const float*)d_in[11];
    const float* bhn  = (const float*)d_in[12];

    unsigned* u0 = (unsigned*)d_ws;             // even parity: 8 replicas
    unsigned* u1 = u0 + NREP * RSTRIDE;         // odd parity:  8 replicas
    // total workspace use: 2 * 8 * 2112 * 4B = 132 KB

    gru_all<<<NBLK, NTHR, 0, stream>>>(x, We, be, Wir, bir, Wiz, biz, Win, bin_,
                                       Whr, Whz, Whn, bhn,
                                       (float*)d_out, u0, u1);
}

// Round 14
// 2209.759 us; speedup vs baseline: 5.6304x; 1.2202x over previous
//
#include <hip/hip_runtime.h>

#define HDIM 2048
#define TSTEPS 1024
#define NBLK 256
#define NTHR 512
#define CPB 8
#define TAGM 0x3FFu
#define NREP 8
#define RSTRIDE 2112u   // u32 per replica = 8KB + 256B (channel decorrelation)
#define SPIN_CAP (1 << 21)   // watchdog: ~1s, never reached in normal runs

typedef unsigned long long ull;

__device__ __forceinline__ int snake_src(int t) {
    int y = t >> 5, p = t & 31;
    return (y & 1) ? (y * 32 + 31 - p) : t;
}
__device__ __forceinline__ float sigmoid_f(float v) {
    return __builtin_amdgcn_rcpf(1.f + __expf(-v));
}
__device__ __forceinline__ float tanh_f(float v) {
    return 1.f - 2.f * __builtin_amdgcn_rcpf(__expf(2.f * v) + 1.f);
}
// broadcast from lane ((lane & 0x38) | G): and_mask=0x18 keeps bits 3,4,
// OR in G (0..7); bit 5 (the 32-lane half) is implicitly preserved.
template<int G>
__device__ __forceinline__ float bcast8(float v) {
    return __uint_as_float((unsigned)__builtin_amdgcn_ds_swizzle(
        (int)__float_as_uint(v), (G << 5) | 0x18));
}

// raw barrier: drain LDS only; vmem (tag prefetch) stays in flight.
#define BAR_RAW() do { asm volatile("s_waitcnt lgkmcnt(0)" ::: "memory"); \
                       __builtin_amdgcn_s_barrier(); } while (0)

// ---------------------------------------------------------------------------
// R14 = R9 byte-identical restore (best verified: 2225us wall / ~2153
// counter). R12/R13 tested and REFUTED the remaining contention hypothesis:
// halving pollers cut FETCH 250->147MB with ZERO dur benefit; halving
// publishers gave nothing; the reshape itself cost +480us (192 weights ->
// AGPR indirection at VGPR_Count=124, and NBLK=128 idles half the CUs).
// Ledger (final):
//   L1 (R1): never scatter the publish — one coalesced wave0-shape store.
//   L2 (R2): publish issued before any thread spins on the next step.
//   L3 (R3): 8x replica spread + s_sleep backoff (the one big hop win).
//   L4 (R4): do NOT widen the publish (16 reps/dwordx2 regressed).
//   L5 (R12/R13): weight arrays MUST be fully-unroll-indexed AND fit arch
//       VGPRs at full occupancy; 96/thread at 512thr is the sweet spot.
// Structure: last-finisher election finalize; self-bypass sNext; tag
// prefetch + immediate reload; single raw barrier/step; watchdog.
// Remaining bound (measured, not a counter roofline): 1023 serial steps x
// ~600cyc device-scope visibility round-trip; VALU 23%, HBM 2%.
// ---------------------------------------------------------------------------
__global__ __launch_bounds__(NTHR, 1) void gru_all(
    const float* __restrict__ x,
    const float* __restrict__ We,  const float* __restrict__ be,
    const float* __restrict__ Wir, const float* __restrict__ bir,
    const float* __restrict__ Wiz, const float* __restrict__ biz,
    const float* __restrict__ Win, const float* __restrict__ bin_,
    const float* __restrict__ Whr, const float* __restrict__ Whz,
    const float* __restrict__ Whn, const float* __restrict__ bhn,
    float* __restrict__ out, unsigned* __restrict__ u0, unsigned* __restrict__ u1)
{
    const int tid  = threadIdx.x;
    const int blk  = blockIdx.x;
    const int c    = tid & 7;
    const int r    = tid >> 3;            // 0..63
    const int col  = blk * CPB + c;
    const int row0 = r * 32;
    const int lane = tid & 63, wv = tid >> 6;

    __shared__ float red[8][6][8];        // init-phase cross-wave reduce
    __shared__ float sX[TSTEPS];          // x in snake order
    __shared__ float sAcc[3][8];          // per-step gate accumulators
    __shared__ float sNext[8];            // own 8 cols of h_t (full precision)
    __shared__ float sAN[8];              // input-path n-term for current t
    __shared__ float sVr[8], sVz[8], sVn[8];   // rank-1 row-sums (const)
    __shared__ float sCr[8], sCz[8], sCn[8];   // bias-path consts
    __shared__ float sBh[8];                   // bhn consts
    __shared__ unsigned sCnt;             // waves-done counter

    // ---- one-time: x (snake order) into LDS ----
    for (int i = tid; i < TSTEPS; i += NTHR) sX[i] = x[snake_src(i)];
    if (tid == 0) sCnt = 0u;

    // ---- recurrent weights into registers (one-time; FULL unroll) ----
    float wr[32], wz[32], wn[32];
#pragma unroll
    for (int k = 0; k < 32; ++k) {
        size_t off = (size_t)(row0 + k) * HDIM + col;
        wr[k] = Whr[off];
        wz[k] = Whz[off];
        wn[k] = Whn[off];
    }

    // ---- rank-1 input-path constants (We/be direct from global) ----
    float eR=0,eZ=0,eN=0,bRa=0,bZa=0,bNa=0;
#pragma unroll 8
    for (int k = 0; k < 32; ++k) {
        int row = row0 + k;
        size_t off = (size_t)row * HDIM + col;
        float we = We[row], bb = be[row];
        float w0 = Wir[off], w1 = Wiz[off], w2 = Win[off];
        eR  = fmaf(we, w0, eR);  bRa = fmaf(bb, w0, bRa);
        eZ  = fmaf(we, w1, eZ);  bZa = fmaf(bb, w1, bZa);
        eN  = fmaf(we, w2, eN);  bNa = fmaf(bb, w2, bNa);
    }
#pragma unroll
    for (int m = 8; m < 64; m <<= 1) {
        eR  += __shfl_xor(eR,  m, 64); eZ  += __shfl_xor(eZ,  m, 64);
        eN  += __shfl_xor(eN,  m, 64); bRa += __shfl_xor(bRa, m, 64);
        bZa += __shfl_xor(bZa, m, 64); bNa += __shfl_xor(bNa, m, 64);
    }
    if (lane < 8) {
        red[wv][0][lane]=eR;  red[wv][1][lane]=eZ;  red[wv][2][lane]=eN;
        red[wv][3][lane]=bRa; red[wv][4][lane]=bZa; red[wv][5][lane]=bNa;
    }
    __syncthreads();   // red + sX staged

    unsigned pk1 = 0;
    if (tid < 8) {
        float vrc=0,vzc=0,vnc=0,crc=0,czc=0,cnc=0;
#pragma unroll
        for (int w = 0; w < 8; ++w) {
            vrc += red[w][0][tid]; vzc += red[w][1][tid]; vnc += red[w][2][tid];
            crc += red[w][3][tid]; czc += red[w][4][tid]; cnc += red[w][5][tid];
        }
        crc += bir[col]; czc += biz[col]; cnc += bin_[col];
        float bhc = bhn[col];

        // constants -> LDS so ANY wave can finalize/re-init
        sVr[tid]=vrc; sVz[tid]=vzc; sVn[tid]=vnc;
        sCr[tid]=crc; sCz[tid]=czc; sCn[tid]=cnc; sBh[tid]=bhc;

        // ---- step 0: h_0 == 0, fully local; h_1 with tag 1 ----
        float x0 = sX[0];
        float ar = fmaf(x0, vrc, crc);
        float az = fmaf(x0, vzc, czc);
        float an = fmaf(x0, vnc, cnc);
        float rg = sigmoid_f(ar), zg = sigmoid_f(az);
        float ng = tanh_f(fmaf(rg, bhc, an));
        float h1 = (1.f - zg) * ng;
        pk1 = ((__float_as_uint(h1) + 512u) & ~TAGM) | 1u;
        sNext[tid] = h1;                  // self-bypass seed for t=1

        // seed t=1 accumulators + n-term
        float x1 = sX[1];
        sAcc[0][tid] = fmaf(x1, vrc, crc);
        sAcc[1][tid] = fmaf(x1, vzc, czc);
        sAN[tid]     = fmaf(x1, vnc, cnc);
        sAcc[2][tid] = bhc;
    }
    // replicated step-0 publish: one dword per wave0 lane (R3-exact shape)
    if (wv == 0) {
        unsigned pkb = __shfl(pk1, lane & 7, 64);
        __hip_atomic_store(&u1[(unsigned)(lane >> 3) * RSTRIDE + (unsigned)blk * 8u + (unsigned)(lane & 7)],
                           pkb, __ATOMIC_RELAXED, __HIP_MEMORY_SCOPE_AGENT);
    }
    __syncthreads();   // LDS state + publish issued before anyone polls

    const ull  M2     = 0x000003FF000003FFull;
    const ull  repoff = (ull)(blk & 7) * (RSTRIDE / 2);   // ull units
    const bool selfcol = ((tid >> 1) == blk);             // polls own 8 cols
    int alive = 1;     // watchdog flag: once 0, never poll again

    // ---- initial prefetch for t=1 ----
    ull v0p, v1p;
    {
        const ull* pp1 = (const ull*)u1 + repoff + 2 * tid;
        v0p = __hip_atomic_load(&pp1[0], __ATOMIC_RELAXED, __HIP_MEMORY_SCOPE_AGENT);
        v1p = __hip_atomic_load(&pp1[1], __ATOMIC_RELAXED, __HIP_MEMORY_SCOPE_AGENT);
    }

    for (int t = 1; t < TSTEPS; ++t) {
        const unsigned* pin  = (t & 1) ? u1 : u0;
        unsigned*       pout = (t & 1) ? u0 : u1;
        const unsigned  tg   = (unsigned)t & TAGM;
        const ull       tg2  = ((ull)tg << 32) | (ull)tg;

        float hr0, hr1, hr2, hr3;
        if (selfcol) {
            // own columns: values live in LDS, skip the L3 round-trip
            const float* sn = &sNext[(tid & 1) * 4];
            hr0 = sn[0]; hr1 = sn[1]; hr2 = sn[2]; hr3 = sn[3];
        } else {
            ull v0 = v0p, v1 = v1p;
            if (((v0 ^ tg2) | (v1 ^ tg2)) & M2) {
                const ull* pp = (const ull*)pin + repoff + 2 * tid;
                // immediate reload (no sleep): prefetch is usually stale-by-
                // timing; a publish may have landed during our FMA phase.
                v0 = __hip_atomic_load(&pp[0], __ATOMIC_RELAXED, __HIP_MEMORY_SCOPE_AGENT);
                v1 = __hip_atomic_load(&pp[1], __ATOMIC_RELAXED, __HIP_MEMORY_SCOPE_AGENT);
                if ((((v0 ^ tg2) | (v1 ^ tg2)) & M2) && alive) {
                    int guard = 0;
                    do {
                        __builtin_amdgcn_s_sleep(1);
                        v0 = __hip_atomic_load(&pp[0], __ATOMIC_RELAXED, __HIP_MEMORY_SCOPE_AGENT);
                        v1 = __hip_atomic_load(&pp[1], __ATOMIC_RELAXED, __HIP_MEMORY_SCOPE_AGENT);
                        if (++guard > SPIN_CAP) { alive = 0; break; }
                    } while (((v0 ^ tg2) | (v1 ^ tg2)) & M2);
                }
            }
            hr0 = __uint_as_float((unsigned)v0         & ~TAGM);
            hr1 = __uint_as_float((unsigned)(v0 >> 32) & ~TAGM);
            hr2 = __uint_as_float((unsigned)v1         & ~TAGM);
            hr3 = __uint_as_float((unsigned)(v1 >> 32) & ~TAGM);
        }

        // ---- 32 intra-group swizzle broadcasts + 96 FMAs (no barrier) ----
        float a0 = 0.f, a1 = 0.f, a2 = 0.f;
#define GRP(G) { \
        float h0 = bcast8<G>(hr0), h1 = bcast8<G>(hr1); \
        float h2 = bcast8<G>(hr2), h3 = bcast8<G>(hr3); \
        a0 = fmaf(h0, wr[4*G+0], a0); a1 = fmaf(h0, wz[4*G+0], a1); a2 = fmaf(h0, wn[4*G+0], a2); \
        a0 = fmaf(h1, wr[4*G+1], a0); a1 = fmaf(h1, wz[4*G+1], a1); a2 = fmaf(h1, wn[4*G+1], a2); \
        a0 = fmaf(h2, wr[4*G+2], a0); a1 = fmaf(h2, wz[4*G+2], a1); a2 = fmaf(h2, wn[4*G+2], a2); \
        a0 = fmaf(h3, wr[4*G+3], a0); a1 = fmaf(h3, wz[4*G+3], a1); a2 = fmaf(h3, wn[4*G+3], a2); }
        GRP(0) GRP(1) GRP(2) GRP(3) GRP(4) GRP(5) GRP(6) GRP(7)
#undef GRP

        // ---- reduce over the 8 groups of this wave ----
#pragma unroll
        for (int m = 8; m < 64; m <<= 1) {
            a0 += __shfl_xor(a0, m, 64);
            a1 += __shfl_xor(a1, m, 64);
            a2 += __shfl_xor(a2, m, 64);
        }
        if (lane < 8) {
            atomicAdd(&sAcc[0][lane], a0);
            atomicAdd(&sAcc[1][lane], a1);
            atomicAdd(&sAcc[2][lane], a2);
        }

        // ---- prefetch t+1 slots; stays in flight across the barrier ----
        {
            const ull* ppn = (const ull*)pout + repoff + 2 * tid;
            v0p = __hip_atomic_load(&ppn[0], __ATOMIC_RELAXED, __HIP_MEMORY_SCOPE_AGENT);
            v1p = __hip_atomic_load(&ppn[1], __ATOMIC_RELAXED, __HIP_MEMORY_SCOPE_AGENT);
        }

        // ---- last-finisher election: wave seeing old==7 finalizes NOW ----
        unsigned oldv = 0;
        if (lane == 0) oldv = atomicAdd(&sCnt, 1u);
        oldv = __builtin_amdgcn_readfirstlane(oldv);
        if (oldv == 7u) {
            float hnew = 0.f; unsigned pk = 0;
            if (lane < 8) {
                float Sr = sAcc[0][lane];         // aR + Whr.h
                float Sz = sAcc[1][lane];         // aZ + Whz.h
                float Sn = sAcc[2][lane];         // bhn + Whn.h
                float hold = sNext[lane];         // own h_t, full precision
                float rg = sigmoid_f(Sr), zg = sigmoid_f(Sz);
                float ng = tanh_f(sAN[lane] + rg * Sn);
                hnew = (1.f - zg) * ng + zg * hold;
                pk = ((__float_as_uint(hnew) + 512u) & ~TAGM)
                   | ((unsigned)(t + 1) & TAGM);
            }
            if (t == TSTEPS - 1) {
                if (lane < 8) out[col] = hnew;
            } else {
                unsigned pkb = __shfl(pk, lane & 7, 64);
                __hip_atomic_store(&pout[(unsigned)(lane >> 3) * RSTRIDE + (unsigned)blk * 8u + (unsigned)(lane & 7)],
                                   pkb, __ATOMIC_RELAXED, __HIP_MEMORY_SCOPE_AGENT);
                if (lane < 8) {   // self-bypass + re-init for t+1
                    sNext[lane] = hnew;
                    float xn = sX[t + 1];
                    sAcc[0][lane] = fmaf(xn, sVr[lane], sCr[lane]);
                    sAcc[1][lane] = fmaf(xn, sVz[lane], sCz[lane]);
                    sAN[lane]     = fmaf(xn, sVn[lane], sCn[lane]);
                    sAcc[2][lane] = sBh[lane];
                }
                if (lane == 0) sCnt = 0u;
            }
        }
        // single barrier: publish issued + LDS re-init done before anyone
        // proceeds to t+1 (ledger L2); vmem prefetch stays in flight.
        BAR_RAW();
    }
}

extern "C" void kernel_launch(void* const* d_in, const int* in_sizes, int n_in,
                              void* d_out, int out_size, void* d_ws, size_t ws_size,
                              hipStream_t stream) {
    const float* x    = (const float*)d_in[0];
    const float* We   = (const float*)d_in[1];
    const float* be   = (const float*)d_in[2];
    const float* Wir  = (const float*)d_in[3];
    const float* bir  = (const float*)d_in[4];
    const float* Wiz  = (const float*)d_in[5];
    const float* biz  = (const float*)d_in[6];
    const float* Win  = (const float*)d_in[7];
    const float* bin_ = (const float*)d_in[8];
    const float* Whr  = (const float*)d_in[9];
    const float* Whz  = (const float*)d_in[10];
    const float* Whn  = (const float*)d_in[11];
    const float* bhn  = (const float*)d_in[12];

    unsigned* u0 = (unsigned*)d_ws;             // even parity: 8 replicas
    unsigned* u1 = u0 + NREP * RSTRIDE;         // odd parity:  8 replicas
    // total workspace use: 2 * 8 * 2112 * 4B = 132 KB

    gru_all<<<NBLK, NTHR, 0, stream>>>(x, We, be, Wir, bir, Wiz, biz, Win, bin_,
                                       Whr, Whz, Whn, bhn,
                                       (float*)d_out, u0, u1);
}